// Round 3
// baseline (29268.146 us; speedup 1.0000x reference)
//
#include <hip/hip_runtime.h>
#include <cstddef>

#define BATCH 256
#define CH    32
#define LR    64
#define UNITS 128
#define DIN   416      // CH + 3*UNITS
#define NCOLS 1024     // 384 (wr) + 512 (wz) + 128 (w_ij padded)

#define HROW  (BATCH*UNITS)        // floats per (slot,row): 32768
#define HSLOT (LR*HROW)            // floats per slot: 2097152

#define OFF_WCAT 0
#define OFF_BCAT (DIN*NCOLS)                 // 425984
#define OFF_HBUF (OFF_BCAT + NCOLS)          // 427008
#define OFF_G    (OFF_HBUF + 3*HSLOT)        // 6718464
// total floats = OFF_G + 64*BATCH*NCOLS = 23495680  (~94 MB)

// ---------------------------------------------------------------------------
// Prep: build Wcat [416][1024] = [wr | wz | pad(w_ij)] and bcat[1024]
// ---------------------------------------------------------------------------
__global__ __launch_bounds__(256) void prep_kernel(
    const float* __restrict__ wr, const float* __restrict__ br,
    const float* __restrict__ wz, const float* __restrict__ bz,
    const float* __restrict__ w_ij, const float* __restrict__ b_ij,
    float* __restrict__ ws) {
  int idx = blockIdx.x * 256 + threadIdx.x;
  if (idx < DIN * NCOLS) {
    int k = idx / NCOLS, n = idx % NCOLS;
    float v;
    if (n < 384)      v = wr[k * 384 + n];
    else if (n < 896) v = wz[k * 512 + (n - 384)];
    else              v = (k >= 384) ? w_ij[(k - 384) * 128 + (n - 896)] : 0.f;
    ws[OFF_WCAT + idx] = v;
  }
  if (idx < NCOLS) {
    float b;
    if (idx < 384)      b = br[idx];
    else if (idx < 896) b = bz[idx - 384];
    else                b = b_ij[idx - 896];
    ws[OFF_BCAT + idx] = b;
  }
}

// ---------------------------------------------------------------------------
// Per-diagonal GEMM: G[cell][b][n] = q[b][:] @ Wcat[:,n] + bcat[n]
// q = [h_top(128) | h_left(128) | h_diag(128) | s_ij(32)]
// Block: 64 batch rows x 128 cols. Grid: ncells * 4 * 8.
// ---------------------------------------------------------------------------
__global__ __launch_bounds__(256) void gemm1_kernel(
    const float* __restrict__ inputs, float* __restrict__ ws, int d, int i0) {
  const int bx = blockIdx.x;
  const int cb = bx & 7;          // col block (128 cols)
  const int rb = (bx >> 3) & 3;   // row block (64 rows)
  const int ci = bx >> 5;         // cell index on diagonal
  const int i = i0 + ci;
  const int j = d - i;
  const int b0 = rb * 64;
  const int n0 = cb * 128;
  const int t = threadIdx.x;

  __shared__ float As[32][64];    // [k][row]
  __shared__ float Bs[32][128];   // [k][col]

  const float* __restrict__ Wcat = ws + OFF_WCAT;
  const float* __restrict__ H1 = ws + OFF_HBUF + (size_t)((d + 2) % 3) * HSLOT; // diag d-1
  const float* __restrict__ H2 = ws + OFF_HBUF + (size_t)((d + 1) % 3) * HSLOT; // diag d-2

  const int tr = t >> 5;          // 0..7 -> rows r0..r0+7
  const int tc = t & 31;          // cols tc*4..+3
  const int r0 = tr * 8;

  float acc[8][4];
#pragma unroll
  for (int a = 0; a < 8; a++)
#pragma unroll
    for (int c = 0; c < 4; c++) acc[a][c] = 0.f;

  for (int kt = 0; kt < 13; kt++) {
    // stage A tile (gather the concatenated q)
#pragma unroll
    for (int s = 0; s < 8; s++) {
      int idx = t + 256 * s;      // 0..2047
      int r = idx & 63;
      int kk = idx >> 6;
      int k = kt * 32 + kk;
      int b = b0 + r;
      float v;
      if (k < 128) {
        v = (i > 0) ? H1[((i - 1) * BATCH + b) * UNITS + k] : 0.f;           // h_top
      } else if (k < 256) {
        v = (j > 0) ? H1[(i * BATCH + b) * UNITS + (k - 128)] : 0.f;         // h_left
      } else if (k < 384) {
        v = (i > 0 && j > 0) ? H2[((i - 1) * BATCH + b) * UNITS + (k - 256)] : 0.f; // h_diag
      } else {
        v = inputs[((b * CH + (k - 384)) * LR + i) * LR + j];                // s_ij
      }
      As[kk][r] = v;
    }
    // stage B tile
#pragma unroll
    for (int s = 0; s < 16; s++) {
      int idx = t + 256 * s;      // 0..4095
      int c = idx & 127;
      int kk = idx >> 7;
      Bs[kk][c] = Wcat[(size_t)(kt * 32 + kk) * NCOLS + n0 + c];
    }
    __syncthreads();
#pragma unroll
    for (int kk = 0; kk < 32; kk++) {
      float4 a01 = *(const float4*)&As[kk][r0];
      float4 a23 = *(const float4*)&As[kk][r0 + 4];
      float4 bv = *(const float4*)&Bs[kk][tc * 4];
      float av[8] = {a01.x, a01.y, a01.z, a01.w, a23.x, a23.y, a23.z, a23.w};
      float bw[4] = {bv.x, bv.y, bv.z, bv.w};
#pragma unroll
      for (int rr = 0; rr < 8; rr++)
#pragma unroll
        for (int cc = 0; cc < 4; cc++) acc[rr][cc] += av[rr] * bw[cc];
    }
    __syncthreads();
  }

  float* __restrict__ G = ws + OFF_G + (size_t)ci * BATCH * NCOLS;
  const float* __restrict__ bcat = ws + OFF_BCAT;
#pragma unroll
  for (int rr = 0; rr < 8; rr++) {
    int b = b0 + r0 + rr;
    int n = n0 + tc * 4;
    float4 bb = *(const float4*)&bcat[n];
    float4 o;
    o.x = acc[rr][0] + bb.x;
    o.y = acc[rr][1] + bb.y;
    o.z = acc[rr][2] + bb.z;
    o.w = acc[rr][3] + bb.w;
    *(float4*)&G[(size_t)b * NCOLS + n] = o;
  }
}

// ---------------------------------------------------------------------------
// Per-diagonal gating: r=sigmoid, z=softmax(4), h_hat=tanh(G_s + rh@U),
// h = zl*hl + zt*ht + zd*hd + zi*hh. Block: 16 batch rows. Grid: ncells*16.
// ---------------------------------------------------------------------------
__global__ __launch_bounds__(256) void gate_kernel(
    float* __restrict__ ws, const float* __restrict__ Umat, int d, int i0) {
  const int bx = blockIdx.x;
  const int wb = bx & 15;
  const int ci = bx >> 4;
  const int i = i0 + ci;
  const int j = d - i;
  const int b0 = wb * 16;
  const int t = threadIdx.x;

  __shared__ float rh[16][388];   // padded (384 % 32 == 0 would 4-way conflict)

  const float* __restrict__ G = ws + OFF_G + (size_t)ci * BATCH * NCOLS;
  const float* __restrict__ H1 = ws + OFF_HBUF + (size_t)((d + 2) % 3) * HSLOT;
  const float* __restrict__ H2 = ws + OFF_HBUF + (size_t)((d + 1) % 3) * HSLOT;
  float* __restrict__ Hout = ws + OFF_HBUF + (size_t)(d % 3) * HSLOT;

  // step 1: rh[r][e] = sigmoid(G[b][e]) * [h_left|h_top|h_diag][e]
#pragma unroll
  for (int s = 0; s < 24; s++) {
    int idx = t + 256 * s;        // 0..6143
    int r = idx / 384, e = idx % 384;
    int b = b0 + r;
    float logit = G[(size_t)b * NCOLS + e];
    float rv = 1.f / (1.f + expf(-logit));
    float hsrc;
    if (e < 128)      hsrc = (j > 0) ? H1[(i * BATCH + b) * UNITS + e] : 0.f;               // h_left
    else if (e < 256) hsrc = (i > 0) ? H1[((i - 1) * BATCH + b) * UNITS + (e - 128)] : 0.f; // h_top
    else              hsrc = (i > 0 && j > 0) ? H2[((i - 1) * BATCH + b) * UNITS + (e - 256)] : 0.f; // h_diag
    rh[r][e] = rv * hsrc;
  }
  __syncthreads();

  // step 2: h_hat pre-act = G[:,896:1024] (has s@w_ij + b_ij) + rh @ U
  const int r = t >> 4;           // 0..15
  const int u0 = (t & 15) * 8;
  const int b = b0 + r;
  float acc[8];
#pragma unroll
  for (int c = 0; c < 8; c++) acc[c] = G[(size_t)b * NCOLS + 896 + u0 + c];
  for (int k = 0; k < 384; k++) {
    float rv = rh[r][k];
    float4 ua = *(const float4*)(Umat + k * 128 + u0);
    float4 ub = *(const float4*)(Umat + k * 128 + u0 + 4);
    acc[0] += rv * ua.x; acc[1] += rv * ua.y; acc[2] += rv * ua.z; acc[3] += rv * ua.w;
    acc[4] += rv * ub.x; acc[5] += rv * ub.y; acc[6] += rv * ub.z; acc[7] += rv * ub.w;
  }

#pragma unroll
  for (int c = 0; c < 8; c++) {
    int u = u0 + c;
    float zi = G[(size_t)b * NCOLS + 384 + u];
    float zl = G[(size_t)b * NCOLS + 512 + u];
    float zt = G[(size_t)b * NCOLS + 640 + u];
    float zd = G[(size_t)b * NCOLS + 768 + u];
    float m = fmaxf(fmaxf(zi, zl), fmaxf(zt, zd));
    float ei = expf(zi - m), el = expf(zl - m), et = expf(zt - m), ed = expf(zd - m);
    float inv = 1.f / (ei + el + et + ed);
    float hl = (j > 0) ? H1[(i * BATCH + b) * UNITS + u] : 0.f;
    float ht = (i > 0) ? H1[((i - 1) * BATCH + b) * UNITS + u] : 0.f;
    float hd = (i > 0 && j > 0) ? H2[((i - 1) * BATCH + b) * UNITS + u] : 0.f;
    float hh = tanhf(acc[c]);
    float h = (el * hl + et * ht + ed * hd + ei * hh) * inv;
    Hout[(i * BATCH + b) * UNITS + u] = h;
  }
}

// ---------------------------------------------------------------------------
__global__ __launch_bounds__(256) void copy_kernel(const float* __restrict__ ws,
                                                   float* __restrict__ out) {
  int idx = blockIdx.x * 256 + threadIdx.x;   // 0..32767
  // h(63,63) written on diagonal 126 -> slot 126 % 3 == 0, row 63
  out[idx] = ws[OFF_HBUF + 0 * HSLOT + 63 * HROW + idx];
}

// ---------------------------------------------------------------------------
extern "C" void kernel_launch(void* const* d_in, const int* in_sizes, int n_in,
                              void* d_out, int out_size, void* d_ws, size_t ws_size,
                              hipStream_t stream) {
  const float* inputs = (const float*)d_in[0];
  const float* wr     = (const float*)d_in[1];
  const float* br     = (const float*)d_in[2];
  const float* wz     = (const float*)d_in[3];
  const float* bz     = (const float*)d_in[4];
  const float* w_ij   = (const float*)d_in[5];
  const float* b_ij   = (const float*)d_in[6];
  const float* Umat   = (const float*)d_in[7];
  float* ws = (float*)d_ws;

  prep_kernel<<<dim3((DIN * NCOLS + 255) / 256), dim3(256), 0, stream>>>(
      wr, br, wz, bz, w_ij, b_ij, ws);

  for (int d = 0; d < 127; d++) {
    int i0 = d > 63 ? d - 63 : 0;
    int i1 = d < 63 ? d : 63;
    int nc = i1 - i0 + 1;
    gemm1_kernel<<<dim3(nc * 32), dim3(256), 0, stream>>>(inputs, ws, d, i0);
    gate_kernel<<<dim3(nc * 16), dim3(256), 0, stream>>>(ws, Umat, d, i0);
  }

  copy_kernel<<<dim3(128), dim3(256), 0, stream>>>(ws, (float*)d_out);
}

// Round 5
// 20111.295 us; speedup vs baseline: 1.4553x; 1.4553x over previous
//
#include <hip/hip_runtime.h>
#include <cstddef>

typedef _Float16 f16;
typedef unsigned int u32;
typedef __attribute__((ext_vector_type(8))) _Float16 half8;
typedef __attribute__((ext_vector_type(4))) float f32x4;

#define BATCH 256
#define CH    32
#define LR    64
#define UNITS 128
#define DIN   416     // CH + 3*UNITS, = 13*32
#define NC    1024    // 384 wr | 512 wz | 128 w_ij(padded)
#define KU    384     // rh@U inner dim, = 12*32

// ---- ws byte offsets ------------------------------------------------------
#define OFF_BH   0ull                           // f16 [1024][416]  Wcat^T hi
#define OFF_BL   (OFF_BH + 1024ull*DIN*2)       // f16 [1024][416]  Wcat^T lo
#define OFF_BC   (OFF_BL + 1024ull*DIN*2)       // f32 [1024] bias
#define OFF_UH   (OFF_BC + 4096ull)             // f16 [128][384]   U^T hi
#define OFF_UL   (OFF_UH + 128ull*KU*2)         // f16 [128][384]   U^T lo
#define OFF_H    (OFF_UL + 128ull*KU*2)         // u32 [3][64][256][128] packed f16 (hi,lo) h
#define HSLOTW   (64ull*256*128)                // u32 per h slot
#define OFF_G    (OFF_H + 3ull*HSLOTW*4)        // f32 [64][256][1024]
// total ~94.2 MB

static __device__ __forceinline__ f16 f16_from_bits(unsigned short s) {
  union { unsigned short u; f16 h; } c; c.u = s; return c.h;
}
static __device__ __forceinline__ unsigned short f16_bits(f16 h) {
  union { f16 h; unsigned short u; } c; c.h = h; return c.u;
}
static __device__ __forceinline__ float unpack_h(u32 w) {
  return (float)f16_from_bits((unsigned short)(w & 0xffffu)) +
         (float)f16_from_bits((unsigned short)(w >> 16));
}
static __device__ __forceinline__ u32 pack_h(float v) {
  f16 hi = (f16)v;
  f16 lo = (f16)(v - (float)hi);
  return (u32)f16_bits(hi) | ((u32)f16_bits(lo) << 16);
}
static __device__ __forceinline__ float fast_tanh(float x) {
  float e = __expf(-2.f * fabsf(x));
  float t = (1.f - e) / (1.f + e);
  return copysignf(t, x);
}

// ---------------------------------------------------------------------------
// Prep: split weights to f16 hi/lo, transposed to [n][k]; bias concat.
// ---------------------------------------------------------------------------
__global__ __launch_bounds__(256) void prep_kernel(
    const float* __restrict__ wr, const float* __restrict__ br,
    const float* __restrict__ wz, const float* __restrict__ bz,
    const float* __restrict__ w_ij, const float* __restrict__ b_ij,
    const float* __restrict__ U, char* __restrict__ ws) {
  int idx = blockIdx.x * 256 + threadIdx.x;
  if (idx < DIN * NC) {
    int k = idx / NC, n = idx % NC;
    float v;
    if (n < 384)      v = wr[k * 384 + n];
    else if (n < 896) v = wz[k * 512 + (n - 384)];
    else              v = (k >= 384) ? w_ij[(k - 384) * 128 + (n - 896)] : 0.f;
    f16 hi = (f16)v;
    f16 lo = (f16)(v - (float)hi);
    ((f16*)(ws + OFF_BH))[(size_t)n * DIN + k] = hi;
    ((f16*)(ws + OFF_BL))[(size_t)n * DIN + k] = lo;
  }
  if (idx < KU * UNITS) {
    int k = idx / UNITS, n = idx % UNITS;
    float v = U[k * UNITS + n];
    f16 hi = (f16)v;
    f16 lo = (f16)(v - (float)hi);
    ((f16*)(ws + OFF_UH))[(size_t)n * KU + k] = hi;
    ((f16*)(ws + OFF_UL))[(size_t)n * KU + k] = lo;
  }
  if (idx < NC) {
    float b;
    if (idx < 384)      b = br[idx];
    else if (idx < 896) b = bz[idx - 384];
    else                b = b_ij[idx - 896];
    ((float*)(ws + OFF_BC))[idx] = b;
  }
}

// ---------------------------------------------------------------------------
// GEMM: G[cell][b][n] = q @ Wcat + bias, 3-term f16 hi/lo MFMA.
// q = [h_top | h_left | h_diag | s_ij]. Block: 128 rows x 128 cols, 4 waves.
// Grid: nc * 16  (bx: cb=bx&7 colblk, rb=(bx>>3)&1 rowblk, ci=bx>>4)
// ---------------------------------------------------------------------------
__global__ __launch_bounds__(256) void gemm_kernel(
    const float* __restrict__ inputs, char* __restrict__ ws, int d, int i0) {
  const int bx = blockIdx.x;
  const int cb = bx & 7, rb = (bx >> 3) & 1, ci = bx >> 4;
  const int i = i0 + ci, j = d - i;
  const int b0 = rb * 128, n0 = cb * 128;
  const int t = threadIdx.x;

  // +8 f16 row pad -> frag reads ~2-way bank aliasing (free)
  __shared__ f16 Ah[128][40], Al[128][40], Bhs[128][40], Bls[128][40];

  const u32* __restrict__ H1 = (const u32*)(ws + OFF_H) + (size_t)((d + 2) % 3) * HSLOTW;
  const u32* __restrict__ H2 = (const u32*)(ws + OFF_H) + (size_t)((d + 1) % 3) * HSLOTW;
  const f16* __restrict__ BhT = (const f16*)(ws + OFF_BH);
  const f16* __restrict__ BlT = (const f16*)(ws + OFF_BL);

  const int w = t >> 6, lane = t & 63;
  const int wrow = (w >> 1) * 64, wcol = (w & 1) * 64;
  const int lm = lane & 15, ksl = lane >> 4;

  f32x4 acc[4][4];
#pragma unroll
  for (int mi = 0; mi < 4; mi++)
#pragma unroll
    for (int ni = 0; ni < 4; ni++)
#pragma unroll
      for (int r = 0; r < 4; r++) acc[mi][ni][r] = 0.f;

  const int sr = t >> 1;        // staging row 0..127
  const int sh = (t & 1) * 16;  // k offset within 32-tile

  for (int kt = 0; kt < 13; kt++) {
    // ---- stage A (q gather; h comes pre-split as packed f16 pairs)
    {
      int b = b0 + sr;
      f16 hi[16] __attribute__((aligned(16)));
      f16 lo[16] __attribute__((aligned(16)));
      if (kt < 12) {
        const u32* src; int row, base; bool valid;
        if (kt < 4)      { src = H1; row = i - 1; base = 0;   valid = (i > 0); }            // h_top
        else if (kt < 8) { src = H1; row = i;     base = 128; valid = (j > 0); }            // h_left
        else             { src = H2; row = i - 1; base = 256; valid = (i > 0 && j > 0); }   // h_diag
        if (valid) {
          const u32* p = src + ((size_t)row * BATCH + b) * UNITS + (kt * 32 + sh - base);
#pragma unroll
          for (int q = 0; q < 16; q++) {
            u32 wv = p[q];
            hi[q] = f16_from_bits((unsigned short)(wv & 0xffffu));
            lo[q] = f16_from_bits((unsigned short)(wv >> 16));
          }
        } else {
#pragma unroll
          for (int q = 0; q < 16; q++) { hi[q] = (f16)0.f; lo[q] = (f16)0.f; }
        }
      } else {  // s_ij (runtime split, 1 of 13 tiles)
#pragma unroll
        for (int q = 0; q < 16; q++) {
          int c = sh + q;
          float v = inputs[(((size_t)b * CH + c) * LR + i) * LR + j];
          f16 h = (f16)v; hi[q] = h; lo[q] = (f16)(v - (float)h);
        }
      }
      *(half8*)&Ah[sr][sh]     = *(half8*)&hi[0];
      *(half8*)&Ah[sr][sh + 8] = *(half8*)&hi[8];
      *(half8*)&Al[sr][sh]     = *(half8*)&lo[0];
      *(half8*)&Al[sr][sh + 8] = *(half8*)&lo[8];
    }
    // ---- stage B (row copy from pre-split transposed weights)
    {
      const f16* ph = BhT + (size_t)(n0 + sr) * DIN + kt * 32 + sh;
      const f16* pl = BlT + (size_t)(n0 + sr) * DIN + kt * 32 + sh;
      *(half8*)&Bhs[sr][sh]     = *(const half8*)ph;
      *(half8*)&Bhs[sr][sh + 8] = *(const half8*)(ph + 8);
      *(half8*)&Bls[sr][sh]     = *(const half8*)pl;
      *(half8*)&Bls[sr][sh + 8] = *(const half8*)(pl + 8);
    }
    __syncthreads();
    // ---- compute: 16 frag reads, 48 MFMA
    half8 afh[4], afl[4], bfh[4], bfl[4];
#pragma unroll
    for (int mi = 0; mi < 4; mi++) {
      afh[mi] = *(half8*)&Ah[wrow + mi * 16 + lm][ksl * 8];
      afl[mi] = *(half8*)&Al[wrow + mi * 16 + lm][ksl * 8];
    }
#pragma unroll
    for (int ni = 0; ni < 4; ni++) {
      bfh[ni] = *(half8*)&Bhs[wcol + ni * 16 + lm][ksl * 8];
      bfl[ni] = *(half8*)&Bls[wcol + ni * 16 + lm][ksl * 8];
    }
#pragma unroll
    for (int mi = 0; mi < 4; mi++)
#pragma unroll
      for (int ni = 0; ni < 4; ni++) {
        acc[mi][ni] = __builtin_amdgcn_mfma_f32_16x16x32_f16(afh[mi], bfh[ni], acc[mi][ni], 0, 0, 0);
        acc[mi][ni] = __builtin_amdgcn_mfma_f32_16x16x32_f16(afl[mi], bfh[ni], acc[mi][ni], 0, 0, 0);
        acc[mi][ni] = __builtin_amdgcn_mfma_f32_16x16x32_f16(afh[mi], bfl[ni], acc[mi][ni], 0, 0, 0);
      }
    __syncthreads();
  }

  // ---- epilogue: C/D map col=lane&15, row=(lane>>4)*4+reg (HW-verified)
  float* __restrict__ G = (float*)(ws + OFF_G) + (size_t)ci * BATCH * NC;
  const float* __restrict__ bc = (const float*)(ws + OFF_BC);
#pragma unroll
  for (int mi = 0; mi < 4; mi++)
#pragma unroll
    for (int ni = 0; ni < 4; ni++) {
      int n = n0 + wcol + ni * 16 + lm;
      float bb = bc[n];
#pragma unroll
      for (int r = 0; r < 4; r++) {
        int b = b0 + wrow + mi * 16 + ksl * 4 + r;
        G[(size_t)b * NC + n] = acc[mi][ni][r] + bb;
      }
    }
}

// ---------------------------------------------------------------------------
// Gate: rh = sigmoid(G[:,:384]) * [h_left|h_top|h_diag]; M = rh@U (3-term
// f16 MFMA); h = softmax4(z) combine with tanh(G_s + M). Block: 128 rows,
// full 128 cols, 4 waves. Grid: nc * 2.
// ---------------------------------------------------------------------------
__global__ __launch_bounds__(256) void gate_kernel(char* __restrict__ ws, int d, int i0) {
  const int bx = blockIdx.x;
  const int rb = bx & 1, ci = bx >> 1;
  const int i = i0 + ci, j = d - i;
  const int b0 = rb * 128;
  const int t = threadIdx.x;

  __shared__ f16 Rh[128][40], Rl[128][40], Uhs[128][40], Uls[128][40];

  float* __restrict__ G = (float*)(ws + OFF_G) + (size_t)ci * BATCH * NC;
  const u32* __restrict__ H1 = (const u32*)(ws + OFF_H) + (size_t)((d + 2) % 3) * HSLOTW;
  const u32* __restrict__ H2 = (const u32*)(ws + OFF_H) + (size_t)((d + 1) % 3) * HSLOTW;
  u32* __restrict__ Hout = (u32*)(ws + OFF_H) + (size_t)(d % 3) * HSLOTW;
  const f16* __restrict__ UhT = (const f16*)(ws + OFF_UH);
  const f16* __restrict__ UlT = (const f16*)(ws + OFF_UL);

  const int w = t >> 6, lane = t & 63;
  const int wrow = (w >> 1) * 64, wcol = (w & 1) * 64;
  const int lm = lane & 15, ksl = lane >> 4;

  f32x4 acc[4][4];
#pragma unroll
  for (int mi = 0; mi < 4; mi++)
#pragma unroll
    for (int ni = 0; ni < 4; ni++)
#pragma unroll
      for (int r = 0; r < 4; r++) acc[mi][ni][r] = 0.f;

  const int sr = t >> 1;
  const int sh = (t & 1) * 16;

  for (int kt = 0; kt < 12; kt++) {
    // ---- stage rh tile (sigmoid in f32, split to f16 pair)
    {
      int b = b0 + sr;
      f16 hi[16] __attribute__((aligned(16)));
      f16 lo[16] __attribute__((aligned(16)));
      const u32* src; int row, base; bool valid;
      if (kt < 4)      { src = H1; row = i;     base = 0;   valid = (j > 0); }            // h_left
      else if (kt < 8) { src = H1; row = i - 1; base = 128; valid = (i > 0); }            // h_top
      else             { src = H2; row = i - 1; base = 256; valid = (i > 0 && j > 0); }   // h_diag
      if (valid) {
        const u32* p = src + ((size_t)row * BATCH + b) * UNITS + (kt * 32 + sh - base);
        const float* g = G + (size_t)b * NC + kt * 32 + sh;
#pragma unroll
        for (int q = 0; q < 16; q++) {
          float rv = 1.f / (1.f + __expf(-g[q]));
          float v = rv * unpack_h(p[q]);
          f16 h = (f16)v; hi[q] = h; lo[q] = (f16)(v - (float)h);
        }
      } else {
#pragma unroll
        for (int q = 0; q < 16; q++) { hi[q] = (f16)0.f; lo[q] = (f16)0.f; }
      }
      *(half8*)&Rh[sr][sh]     = *(half8*)&hi[0];
      *(half8*)&Rh[sr][sh + 8] = *(half8*)&hi[8];
      *(half8*)&Rl[sr][sh]     = *(half8*)&lo[0];
      *(half8*)&Rl[sr][sh + 8] = *(half8*)&lo[8];
    }
    // ---- stage U tile
    {
      const f16* ph = UhT + (size_t)sr * KU + kt * 32 + sh;
      const f16* pl = UlT + (size_t)sr * KU + kt * 32 + sh;
      *(half8*)&Uhs[sr][sh]     = *(const half8*)ph;
      *(half8*)&Uhs[sr][sh + 8] = *(const half8*)(ph + 8);
      *(half8*)&Uls[sr][sh]     = *(const half8*)pl;
      *(half8*)&Uls[sr][sh + 8] = *(const half8*)(pl + 8);
    }
    __syncthreads();
    half8 afh[4], afl[4], bfh[4], bfl[4];
#pragma unroll
    for (int mi = 0; mi < 4; mi++) {
      afh[mi] = *(half8*)&Rh[wrow + mi * 16 + lm][ksl * 8];
      afl[mi] = *(half8*)&Rl[wrow + mi * 16 + lm][ksl * 8];
    }
#pragma unroll
    for (int ni = 0; ni < 4; ni++) {
      bfh[ni] = *(half8*)&Uhs[wcol + ni * 16 + lm][ksl * 8];
      bfl[ni] = *(half8*)&Uls[wcol + ni * 16 + lm][ksl * 8];
    }
#pragma unroll
    for (int mi = 0; mi < 4; mi++)
#pragma unroll
      for (int ni = 0; ni < 4; ni++) {
        acc[mi][ni] = __builtin_amdgcn_mfma_f32_16x16x32_f16(afh[mi], bfh[ni], acc[mi][ni], 0, 0, 0);
        acc[mi][ni] = __builtin_amdgcn_mfma_f32_16x16x32_f16(afl[mi], bfh[ni], acc[mi][ni], 0, 0, 0);
        acc[mi][ni] = __builtin_amdgcn_mfma_f32_16x16x32_f16(afh[mi], bfl[ni], acc[mi][ni], 0, 0, 0);
      }
    __syncthreads();
  }

  // ---- epilogue: softmax gates + tanh + combine, write packed h
#pragma unroll
  for (int mi = 0; mi < 4; mi++)
#pragma unroll
    for (int r = 0; r < 4; r++) {
      int b = b0 + wrow + mi * 16 + ksl * 4 + r;
      const float* Gr = G + (size_t)b * NC;
      size_t hbase = ((size_t)i * BATCH + b) * UNITS;
#pragma unroll
      for (int ni = 0; ni < 4; ni++) {
        int u = wcol + ni * 16 + lm;
        float zi = Gr[384 + u], zl = Gr[512 + u], zt = Gr[640 + u], zd = Gr[768 + u];
        float mm = fmaxf(fmaxf(zi, zl), fmaxf(zt, zd));
        float ei = __expf(zi - mm), el = __expf(zl - mm),
              et = __expf(zt - mm), ed = __expf(zd - mm);
        float inv = 1.f / (ei + el + et + ed);
        float hl = (j > 0) ? unpack_h(H1[((size_t)i * BATCH + b) * UNITS + u]) : 0.f;
        float ht = (i > 0) ? unpack_h(H1[((size_t)(i - 1) * BATCH + b) * UNITS + u]) : 0.f;
        float hd = (i > 0 && j > 0) ? unpack_h(H2[((size_t)(i - 1) * BATCH + b) * UNITS + u]) : 0.f;
        float hh = fast_tanh(Gr[896 + u] + acc[mi][ni][r]);
        float h = (el * hl + et * ht + ed * hd + ei * hh) * inv;
        Hout[hbase + u] = pack_h(h);
      }
    }
}

// ---------------------------------------------------------------------------
__global__ __launch_bounds__(256) void copy_kernel(const char* __restrict__ ws,
                                                   float* __restrict__ out) {
  int idx = blockIdx.x * 256 + threadIdx.x;  // 0..32767 = b*128+u
  // h(63,63) on diagonal 126 -> slot 126%3==0, row 63
  const u32* H0 = (const u32*)(ws + OFF_H);
  out[idx] = unpack_h(H0[(size_t)63 * BATCH * UNITS + idx]);
}

// ---------------------------------------------------------------------------
extern "C" void kernel_launch(void* const* d_in, const int* in_sizes, int n_in,
                              void* d_out, int out_size, void* d_ws, size_t ws_size,
                              hipStream_t stream) {
  const float* inputs = (const float*)d_in[0];
  const float* wr     = (const float*)d_in[1];
  const float* br     = (const float*)d_in[2];
  const float* wz     = (const float*)d_in[3];
  const float* bz     = (const float*)d_in[4];
  const float* w_ij   = (const float*)d_in[5];
  const float* b_ij   = (const float*)d_in[6];
  const float* Umat   = (const float*)d_in[7];
  char* ws = (char*)d_ws;

  prep_kernel<<<dim3((DIN * NC + 255) / 256), dim3(256), 0, stream>>>(
      wr, br, wz, bz, w_ij, b_ij, Umat, ws);

  for (int d = 0; d < 127; d++) {
    int i0 = d > 63 ? d - 63 : 0;
    int i1 = d < 63 ? d : 63;
    int nc = i1 - i0 + 1;
    gemm_kernel<<<dim3(nc * 16), dim3(256), 0, stream>>>(inputs, ws, d, i0);
    gate_kernel<<<dim3(nc * 2), dim3(256), 0, stream>>>(ws, d, i0);
  }

  copy_kernel<<<dim3(128), dim3(256), 0, stream>>>(ws, (float*)d_out);
}

// Round 11
// 12726.993 us; speedup vs baseline: 2.2997x; 1.5802x over previous
//
#include <hip/hip_runtime.h>
#include <cstddef>

typedef _Float16 f16;
typedef unsigned int u32;
typedef __attribute__((ext_vector_type(8))) _Float16 half8;
typedef __attribute__((ext_vector_type(4))) _Float16 half4;
typedef __attribute__((ext_vector_type(4))) float f32x4;

#define BATCH 256
#define CH    32
#define LR    64
#define UNITS 128
#define DIN   416
#define NC    1024
#define KU    384

// ---- ws byte offsets (total 93,982,720 == round-3-proven size) ------------
#define OFF_WH   0ull                      // f16 [896][416]  Wcat^T hi (wr|wz cols)
#define OFF_WL   745472ull                 // f16 [896][416]  lo
#define OFF_W3H  1490944ull                // f16 [128][32]   w_ij block (k 384..416) hi
#define OFF_W3L  1499136ull                // lo
#define OFF_BC   1507328ull                // f32 [1024] bias
#define OFF_UH   1511424ull                // f16 [128][384]  U^T hi
#define OFF_UL   1609728ull                // lo
#define OFF_HHI  1708032ull                // f16 [3][64][256][128] h hi planes
#define HPLANE   4194304ull                // bytes per slot plane
#define OFF_HLO  (OFF_HHI + 3ull*HPLANE)   // h lo planes
#define OFF_G    (OFF_HLO + 3ull*HPLANE)   // f32 [64][256][1024]

static __device__ __forceinline__ void gll16(const void* g, void* l) {
  __builtin_amdgcn_global_load_lds(
      (const __attribute__((address_space(1))) u32*)g,
      (__attribute__((address_space(3))) u32*)l, 16, 0, 0);
}
static __device__ __forceinline__ float fast_tanh(float x) {
  float e = __expf(-2.f * fabsf(x));
  float t = (1.f - e) / (1.f + e);
  return copysignf(t, x);
}

// ---------------------------------------------------------------------------
__global__ __launch_bounds__(256) void prep_kernel(
    const float* __restrict__ wr, const float* __restrict__ br,
    const float* __restrict__ wz, const float* __restrict__ bz,
    const float* __restrict__ w_ij, const float* __restrict__ b_ij,
    const float* __restrict__ U, char* __restrict__ ws) {
  int idx = blockIdx.x * 256 + threadIdx.x;
  if (idx < 896 * DIN) {                       // main W: [n][k], n<896
    int n = idx / DIN, k = idx % DIN;
    float v = (n < 384) ? wr[k * 384 + n] : wz[k * 512 + (n - 384)];
    f16 hi = (f16)v;
    ((f16*)(ws + OFF_WH))[idx] = hi;
    ((f16*)(ws + OFF_WL))[idx] = (f16)(v - (float)hi);
  }
  if (idx < 128 * 32) {                        // w_ij block [n3][k3]
    int n3 = idx >> 5, k3 = idx & 31;
    float v = w_ij[k3 * UNITS + n3];
    f16 hi = (f16)v;
    ((f16*)(ws + OFF_W3H))[idx] = hi;
    ((f16*)(ws + OFF_W3L))[idx] = (f16)(v - (float)hi);
  }
  if (idx < UNITS * KU) {                      // U^T [n][k]
    int n = idx / KU, k = idx % KU;
    float v = U[k * UNITS + n];
    f16 hi = (f16)v;
    ((f16*)(ws + OFF_UH))[idx] = hi;
    ((f16*)(ws + OFF_UL))[idx] = (f16)(v - (float)hi);
  }
  if (idx < NC) {
    float b;
    if (idx < 384)      b = br[idx];
    else if (idx < 896) b = bz[idx - 384];
    else                b = b_ij[idx - 896];
    ((float*)(ws + OFF_BC))[idx] = b;
  }
}

// ---------------------------------------------------------------------------
// GEMM: G = q @ Wcat + bias (3-term f16 split). 128x128 tile, 4 waves.
// Staging via global_load_lds w/ chunk swizzle p = r*4 + (ksl ^ ((r>>1)&3)).
// Grid: nc*16 (cb=bx&7, rb=(bx>>3)&1, ci=bx>>4). Zero k-regions skipped.
// ---------------------------------------------------------------------------
__global__ __launch_bounds__(256) void gemm_kernel(
    const float* __restrict__ inputs, char* __restrict__ ws, int d, int i0) {
  const int bx = blockIdx.x;
  const int cb = bx & 7, rb = (bx >> 3) & 1, ci = bx >> 4;
  const int i = i0 + ci, j = d - i;
  const int b0 = rb * 128, n0 = cb * 128;
  const int t = threadIdx.x;
  const int w = t >> 6, lane = t & 63;
  const int lm = lane & 15, ksl = lane >> 4;
  const int wrow = (w >> 1) * 64, wcol = (w & 1) * 64;

  __shared__ f16 Ah[4096], Al[4096], Bh[4096], Bl[4096];   // 8 KB each, linear

  // per-lane staging constants: wave w covers chunks w*128 + {0..127}
  const int s0 = w * 128 + lane, s1 = s0 + 64;
  const int r0s = s0 >> 2, k0s = (s0 & 3) ^ ((r0s >> 1) & 3);
  const int r1s = s1 >> 2, k1s = (s1 & 3) ^ ((r1s >> 1) & 3);
  const u32 db0 = (u32)w * 2048u, db1 = db0 + 1024u;
  const int kswz = (ksl ^ ((lm >> 1) & 3)) * 8;            // frag-read swizzle (f16 units)

  const f16* __restrict__ H1h = (const f16*)(ws + OFF_HHI + (size_t)((d + 2) % 3) * HPLANE);
  const f16* __restrict__ H1l = (const f16*)(ws + OFF_HLO + (size_t)((d + 2) % 3) * HPLANE);
  const f16* __restrict__ H2h = (const f16*)(ws + OFF_HHI + (size_t)((d + 1) % 3) * HPLANE);
  const f16* __restrict__ H2l = (const f16*)(ws + OFF_HLO + (size_t)((d + 1) % 3) * HPLANE);
  const f16* __restrict__ Wh  = (const f16*)(ws + OFF_WH);
  const f16* __restrict__ Wl  = (const f16*)(ws + OFF_WL);
  const f16* __restrict__ W3h = (const f16*)(ws + OFF_W3H);
  const f16* __restrict__ W3l = (const f16*)(ws + OFF_W3L);
  const bool vt = (i > 0), vl = (j > 0), vd = (i > 0 && j > 0);

  f32x4 acc[4][4];
#pragma unroll
  for (int mi = 0; mi < 4; mi++)
#pragma unroll
    for (int ni = 0; ni < 4; ni++)
#pragma unroll
      for (int r = 0; r < 4; r++) acc[mi][ni][r] = 0.f;

  for (int kt = (cb == 7 ? 12 : 0); kt < 13; kt++) {
    const bool ok = (kt < 4) ? vt : (kt < 8) ? vl : (kt < 12) ? vd : true;
    if (!ok) continue;                                     // q is zero there

    if (kt < 12) {   // ---- A from h planes (pure DMA)
      const f16 *ph, *pl; int hrow;
      if (kt < 4)      { ph = H1h; pl = H1l; hrow = i - 1; }   // h_top
      else if (kt < 8) { ph = H1h; pl = H1l; hrow = i; }       // h_left
      else             { ph = H2h; pl = H2l; hrow = i - 1; }   // h_diag
      const size_t ab = ((size_t)hrow * BATCH + b0) * UNITS + (size_t)(kt & 3) * 32;
      gll16(ph + ab + r0s * UNITS + k0s * 8, (char*)Ah + db0);
      gll16(ph + ab + r1s * UNITS + k1s * 8, (char*)Ah + db1);
      gll16(pl + ab + r0s * UNITS + k0s * 8, (char*)Al + db0);
      gll16(pl + ab + r1s * UNITS + k1s * 8, (char*)Al + db1);
    } else {         // ---- A = s_ij gather (1 of 13 tiles), swizzled ds_write
      const int r = t >> 1, kp = (t & 1) * 2;
      const int b = b0 + r, sw = (r >> 1) & 3;
#pragma unroll
      for (int c2 = 0; c2 < 2; c2++) {
        const int c = kp + c2;
        half8 hv, lv;
#pragma unroll
        for (int q = 0; q < 8; q++) {
          float v = inputs[((size_t)b * CH + c * 8 + q) * (LR * LR) + i * LR + j];
          f16 h = (f16)v;
          hv[q] = h; lv[q] = (f16)(v - (float)h);
        }
        const int p = r * 4 + (c ^ sw);
        *(half8*)&Ah[p * 8] = hv;
        *(half8*)&Al[p * 8] = lv;
      }
    }
    // ---- B staging
    if (cb < 7) {
      const size_t bb = (size_t)n0 * DIN + (size_t)kt * 32;
      gll16(Wh + bb + r0s * DIN + k0s * 8, (char*)Bh + db0);
      gll16(Wh + bb + r1s * DIN + k1s * 8, (char*)Bh + db1);
      gll16(Wl + bb + r0s * DIN + k0s * 8, (char*)Bl + db0);
      gll16(Wl + bb + r1s * DIN + k1s * 8, (char*)Bl + db1);
    } else {         // kt==12 only; [128][32] layout
      gll16(W3h + r0s * 32 + k0s * 8, (char*)Bh + db0);
      gll16(W3h + r1s * 32 + k1s * 8, (char*)Bh + db1);
      gll16(W3l + r0s * 32 + k0s * 8, (char*)Bl + db0);
      gll16(W3l + r1s * 32 + k1s * 8, (char*)Bl + db1);
    }
    __syncthreads();

    half8 afh[4], afl[4], bfh[4], bfl[4];
#pragma unroll
    for (int mi = 0; mi < 4; mi++) {
      const int ro = (wrow + mi * 16 + lm) * 32 + kswz;
      afh[mi] = *(const half8*)&Ah[ro];
      afl[mi] = *(const half8*)&Al[ro];
    }
#pragma unroll
    for (int ni = 0; ni < 4; ni++) {
      const int ro = (wcol + ni * 16 + lm) * 32 + kswz;
      bfh[ni] = *(const half8*)&Bh[ro];
      bfl[ni] = *(const half8*)&Bl[ro];
    }
#pragma unroll
    for (int mi = 0; mi < 4; mi++)
#pragma unroll
      for (int ni = 0; ni < 4; ni++) {
        acc[mi][ni] = __builtin_amdgcn_mfma_f32_16x16x32_f16(afh[mi], bfh[ni], acc[mi][ni], 0, 0, 0);
        acc[mi][ni] = __builtin_amdgcn_mfma_f32_16x16x32_f16(afl[mi], bfh[ni], acc[mi][ni], 0, 0, 0);
        acc[mi][ni] = __builtin_amdgcn_mfma_f32_16x16x32_f16(afh[mi], bfl[ni], acc[mi][ni], 0, 0, 0);
      }
    __syncthreads();
  }

  float* __restrict__ G = (float*)(ws + OFF_G) + (size_t)ci * BATCH * NC;
  const float* __restrict__ bc = (const float*)(ws + OFF_BC);
#pragma unroll
  for (int mi = 0; mi < 4; mi++)
#pragma unroll
    for (int ni = 0; ni < 4; ni++) {
      const int n = n0 + wcol + ni * 16 + lm;
      const float bb = bc[n];
#pragma unroll
      for (int r = 0; r < 4; r++) {
        const int b = b0 + wrow + mi * 16 + ksl * 4 + r;
        G[(size_t)b * NC + n] = acc[mi][ni][r] + bb;
      }
    }
}

// ---------------------------------------------------------------------------
// Gate: rh = sigmoid(G[:, :384]) * [h_left|h_top|h_diag]; M = rh@U (3-term);
// h = softmax4(z) ⊙ {hl,ht,hd,tanh(Gs+M)}. Block: 32 rows x 128 cols, 4 waves.
// Grid: nc*8.
// ---------------------------------------------------------------------------
__global__ __launch_bounds__(256) void gate_kernel(char* __restrict__ ws, int d, int i0) {
  const int bx = blockIdx.x;
  const int rb = bx & 7, ci = bx >> 3;
  const int i = i0 + ci, j = d - i;
  const int b0 = rb * 32;
  const int t = threadIdx.x;
  const int w = t >> 6, lane = t & 63;
  const int lm = lane & 15, ksl = lane >> 4;
  const int wcol = w * 32;

  __shared__ f16 Rh[32][40], Rl[32][40];   // padded, ds_write path
  __shared__ f16 Uh[4096], Ul[4096];       // linear + swizzle, gll path

  const int s0 = w * 128 + lane, s1 = s0 + 64;
  const int r0s = s0 >> 2, k0s = (s0 & 3) ^ ((r0s >> 1) & 3);
  const int r1s = s1 >> 2, k1s = (s1 & 3) ^ ((r1s >> 1) & 3);
  const u32 db0 = (u32)w * 2048u, db1 = db0 + 1024u;
  const int kswz = (ksl ^ ((lm >> 1) & 3)) * 8;

  float* __restrict__ G = (float*)(ws + OFF_G) + (size_t)ci * BATCH * NC;
  const f16* __restrict__ H1h = (const f16*)(ws + OFF_HHI + (size_t)((d + 2) % 3) * HPLANE);
  const f16* __restrict__ H1l = (const f16*)(ws + OFF_HLO + (size_t)((d + 2) % 3) * HPLANE);
  const f16* __restrict__ H2h = (const f16*)(ws + OFF_HHI + (size_t)((d + 1) % 3) * HPLANE);
  const f16* __restrict__ H2l = (const f16*)(ws + OFF_HLO + (size_t)((d + 1) % 3) * HPLANE);
  f16* __restrict__ Hoh = (f16*)(ws + OFF_HHI + (size_t)(d % 3) * HPLANE);
  f16* __restrict__ Hol = (f16*)(ws + OFF_HLO + (size_t)(d % 3) * HPLANE);
  const f16* __restrict__ UhT = (const f16*)(ws + OFF_UH);
  const f16* __restrict__ UlT = (const f16*)(ws + OFF_UL);
  const bool vt = (i > 0), vlf = (j > 0), vd = (i > 0 && j > 0);

  f32x4 acc[2][2];
#pragma unroll
  for (int mi = 0; mi < 2; mi++)
#pragma unroll
    for (int ni = 0; ni < 2; ni++)
#pragma unroll
      for (int r = 0; r < 4; r++) acc[mi][ni][r] = 0.f;

  const int sr = t >> 3, sk = (t & 7) * 4;   // rh staging: row sr, k sk..sk+3

  for (int kt = 0; kt < 12; kt++) {
    const f16 *ph, *pl; int hrow; bool ok;
    if (kt < 4)      { ph = H1h; pl = H1l; hrow = i;     ok = vlf; }  // h_left
    else if (kt < 8) { ph = H1h; pl = H1l; hrow = i - 1; ok = vt; }   // h_top
    else             { ph = H2h; pl = H2l; hrow = i - 1; ok = vd; }   // h_diag
    if (!ok) continue;
    {
      const int b = b0 + sr;
      const f32x4 g = *(const f32x4*)&G[(size_t)b * NC + kt * 32 + sk];
      const size_t hx = ((size_t)hrow * BATCH + b) * UNITS + (kt & 3) * 32 + sk;
      const half4 h4 = *(const half4*)(ph + hx);
      const half4 l4 = *(const half4*)(pl + hx);
      half4 oh, ol;
#pragma unroll
      for (int q = 0; q < 4; q++) {
        const float rv = 1.f / (1.f + __expf(-g[q]));
        const float v = rv * ((float)h4[q] + (float)l4[q]);
        const f16 h = (f16)v;
        oh[q] = h; ol[q] = (f16)(v - (float)h);
      }
      *(half4*)&Rh[sr][sk] = oh;
      *(half4*)&Rl[sr][sk] = ol;
    }
    {
      const size_t ub = (size_t)kt * 32;
      gll16(UhT + ub + r0s * KU + k0s * 8, (char*)Uh + db0);
      gll16(UhT + ub + r1s * KU + k1s * 8, (char*)Uh + db1);
      gll16(UlT + ub + r0s * KU + k0s * 8, (char*)Ul + db0);
      gll16(UlT + ub + r1s * KU + k1s * 8, (char*)Ul + db1);
    }
    __syncthreads();

    half8 afh[2], afl[2], bfh[2], bfl[2];
#pragma unroll
    for (int mi = 0; mi < 2; mi++) {
      afh[mi] = *(const half8*)&Rh[mi * 16 + lm][ksl * 8];
      afl[mi] = *(const half8*)&Rl[mi * 16 + lm][ksl * 8];
    }
#pragma unroll
    for (int ni = 0; ni < 2; ni++) {
      const int ro = (wcol + ni * 16 + lm) * 32 + kswz;
      bfh[ni] = *(const half8*)&Uh[ro];
      bfl[ni] = *(const half8*)&Ul[ro];
    }
#pragma unroll
    for (int mi = 0; mi < 2; mi++)
#pragma unroll
      for (int ni = 0; ni < 2; ni++) {
        acc[mi][ni] = __builtin_amdgcn_mfma_f32_16x16x32_f16(afh[mi], bfh[ni], acc[mi][ni], 0, 0, 0);
        acc[mi][ni] = __builtin_amdgcn_mfma_f32_16x16x32_f16(afl[mi], bfh[ni], acc[mi][ni], 0, 0, 0);
        acc[mi][ni] = __builtin_amdgcn_mfma_f32_16x16x32_f16(afh[mi], bfl[ni], acc[mi][ni], 0, 0, 0);
      }
    __syncthreads();
  }

  // ---- epilogue
#pragma unroll
  for (int mi = 0; mi < 2; mi++)
#pragma unroll
    for (int r = 0; r < 4; r++) {
      const int b = b0 + mi * 16 + ksl * 4 + r;
      const float* __restrict__ Gr = G + (size_t)b * NC;
      const size_t ho  = ((size_t)i * BATCH + b) * UNITS;        // out & h_left row
      const size_t htb = ((size_t)(i - 1) * BATCH + b) * UNITS;  // h_top / h_diag row
#pragma unroll
      for (int ni = 0; ni < 2; ni++) {
        const int u = wcol + ni * 16 + lm;
        const float zi = Gr[384 + u], zl = Gr[512 + u], zt = Gr[640 + u], zd = Gr[768 + u];
        const float mm = fmaxf(fmaxf(zi, zl), fmaxf(zt, zd));
        const float ei = __expf(zi - mm), el = __expf(zl - mm),
                    et = __expf(zt - mm), ed = __expf(zd - mm);
        const float inv = 1.f / (ei + el + et + ed);
        const float hl = vlf ? (float)H1h[ho + u] + (float)H1l[ho + u] : 0.f;
        const float ht = vt  ? (float)H1h[htb + u] + (float)H1l[htb + u] : 0.f;
        const float hd = vd  ? (float)H2h[htb + u] + (float)H2l[htb + u] : 0.f;
        const float hh = fast_tanh(Gr[896 + u] + acc[mi][ni][r]);
        const float h = (el * hl + et * ht + ed * hd + ei * hh) * inv;
        const f16 hhi = (f16)h;
        Hoh[ho + u] = hhi;
        Hol[ho + u] = (f16)(h - (float)hhi);
      }
    }
}

// ---------------------------------------------------------------------------
__global__ __launch_bounds__(256) void copy_kernel(const char* __restrict__ ws,
                                                   float* __restrict__ out) {
  int idx = blockIdx.x * 256 + threadIdx.x;   // 0..32767 = b*128+u
  // h(63,63) on diagonal 126 -> slot 126%3==0, row 63
  const f16* Hh = (const f16*)(ws + OFF_HHI);
  const f16* Hl = (const f16*)(ws + OFF_HLO);
  const size_t o = (size_t)63 * BATCH * UNITS + idx;
  out[idx] = (float)Hh[o] + (float)Hl[o];
}

// ---------------------------------------------------------------------------
extern "C" void kernel_launch(void* const* d_in, const int* in_sizes, int n_in,
                              void* d_out, int out_size, void* d_ws, size_t ws_size,
                              hipStream_t stream) {
  const float* inputs = (const float*)d_in[0];
  const float* wr     = (const float*)d_in[1];
  const float* br     = (const float*)d_in[2];
  const float* wz     = (const float*)d_in[3];
  const float* bz     = (const float*)d_in[4];
  const float* w_ij   = (const float*)d_in[5];
  const float* b_ij   = (const float*)d_in[6];
  const float* Umat   = (const float*)d_in[7];
  char* ws = (char*)d_ws;

  prep_kernel<<<dim3(1456), dim3(256), 0, stream>>>(
      wr, br, wz, bz, w_ij, b_ij, Umat, ws);

  for (int d = 0; d < 127; d++) {
    int i0 = d > 63 ? d - 63 : 0;
    int i1 = d < 63 ? d : 63;
    int nc = i1 - i0 + 1;
    gemm_kernel<<<dim3(nc * 16), dim3(256), 0, stream>>>(inputs, ws, d, i0);
    gate_kernel<<<dim3(nc * 8), dim3(256), 0, stream>>>(ws, d, i0);
  }

  copy_kernel<<<dim3(128), dim3(256), 0, stream>>>(ws, (float*)d_out);
}